// Round 7
// baseline (380.025 us; speedup 1.0000x reference)
//
#include <hip/hip_runtime.h>
#include <hip/hip_bf16.h>

#define NLAB  24
#define LDIM  256
#define LSEQ  512
#define DDIM  1024
#define NOUT  12288            /* NLAB*LDIM*2 */
#define NEGV  (-10000.0f)
#define MOFF  50331648L        /* 192*512*512 */

typedef __attribute__((ext_vector_type(8))) short short8;
typedef __attribute__((ext_vector_type(4))) float f32x4;
typedef unsigned short u16;
typedef unsigned int   u32;

typedef const __attribute__((address_space(1))) void gvoid_t;
typedef __attribute__((address_space(3))) void lvoid_t;

__device__ __forceinline__ u16 f2bf(float f) {
  u32 u = __builtin_bit_cast(u32, f);
  u32 r = u + 0x7FFFu + ((u >> 16) & 1u);
  return (u16)(r >> 16);
}

__device__ __forceinline__ void g2l16(const u16* g, u16* l) {
  __builtin_amdgcn_global_load_lds((gvoid_t*)g, (lvoid_t*)l, 16, 0, 0);
}

/* ---------------- fp32 -> bf16 conversion of features and w_ff ------------- */
__global__ void cvt_bf16_kernel(const float* __restrict__ feat,
                                const float* __restrict__ wff,
                                u16* __restrict__ fA, u16* __restrict__ fB) {
  const long NA = 4194304L;      /* 4096*1024 */
  const long NB = 12582912L;     /* 12288*1024 */
  const long NQ = (NA + NB) / 4;
  long stride = (long)gridDim.x * blockDim.x;
  for (long i = (long)blockIdx.x * blockDim.x + threadIdx.x; i < NQ; i += stride) {
    long e = i * 4;
    const float* s; u16* d;
    if (e < NA) { s = feat + e;        d = fA + e; }
    else        { s = wff + (e - NA);  d = fB + (e - NA); }
    float4 v = *reinterpret_cast<const float4*>(s);
    ushort4 o;
    o.x = f2bf(v.x); o.y = f2bf(v.y); o.z = f2bf(v.z); o.w = f2bf(v.w);
    *reinterpret_cast<ushort4*>(d) = o;
  }
}

/* ---- r2-verbatim FF GEMM: 256^2 tile, BK=64, 2-phase, 128KB LDS ----------- */
template<int LDK, bool PERM>
__device__ __forceinline__ void stage_tile(const u16* __restrict__ gbase, int row0,
                                           int k0, u16* lbuf, int t) {
#pragma unroll
  for (int l = 0; l < 4; ++l) {
    const int rt = l * 64 + (t >> 3);
    const int ce = ((t & 7) ^ (rt & 7)) << 3;
    int gr = rt;
    if (PERM) gr = (rt & ~31) | ((rt & 15) << 1) | ((rt >> 4) & 1);
    g2l16(gbase + (long)(row0 + gr) * LDK + k0 + ce, lbuf + (l * 512 + t) * 8);
  }
}

#define FRAG_OFF(r, ks, hi) (((r) * 64 + (ks) * 32 + (hi) * 8) ^ (((r) & 7) << 3))

__global__ __launch_bounds__(512, 2)
void ff_gemm256(const u16* __restrict__ A, const u16* __restrict__ B,
                const float* __restrict__ bff,
                u16* __restrict__ sf, u16* __restrict__ ef) {
  __shared__ __align__(16) u16 lds[2][2][16384];    /* 128 KiB */
  const int tid = threadIdx.x, lane = tid & 63, wv = tid >> 6;
  const int wm = wv >> 2, wn = wv & 3;
  const int lr = lane & 15, hi = lane >> 4;

  const int bid = blockIdx.x;
  const int wg  = (bid & 7) * 96 + (bid >> 3);      /* XCD-chunked, bijective */
  const int tm  = wg & 15, tn = wg >> 4;            /* 16 x 48 tiles */
  const int rowA0 = tm * 256, rowB0 = tn * 256;

  f32x4 acc[8][4] = {};

  stage_tile<DDIM, false>(A, rowA0, 0, lds[0][0], tid);
  stage_tile<DDIM, true >(B, rowB0, 0, lds[0][1], tid);
  __syncthreads();

  int buf = 0;
  for (int t = 0; t < 16; ++t) {
    if (t < 15) {
      stage_tile<DDIM, false>(A, rowA0, (t + 1) * 64, lds[buf ^ 1][0], tid);
      stage_tile<DDIM, true >(B, rowB0, (t + 1) * 64, lds[buf ^ 1][1], tid);
    }
    const u16* La = lds[buf][0];
    const u16* Lb = lds[buf][1];
#pragma unroll
    for (int ks = 0; ks < 2; ++ks) {
      short8 af[8], bfr[4];
#pragma unroll
      for (int i = 0; i < 8; ++i) {
        const int r = wm * 128 + i * 16 + lr;
        af[i] = *reinterpret_cast<const short8*>(La + FRAG_OFF(r, ks, hi));
      }
#pragma unroll
      for (int j = 0; j < 4; ++j) {
        const int r = wn * 64 + j * 16 + lr;
        bfr[j] = *reinterpret_cast<const short8*>(Lb + FRAG_OFF(r, ks, hi));
      }
      __builtin_amdgcn_s_setprio(1);
#pragma unroll
      for (int i = 0; i < 8; ++i)
#pragma unroll
        for (int j = 0; j < 4; ++j)
          acc[i][j] = __builtin_amdgcn_mfma_f32_16x16x32_bf16(af[i], bfr[j], acc[i][j], 0, 0, 0);
      __builtin_amdgcn_s_setprio(0);
    }
    __syncthreads();
    buf ^= 1;
  }

  /* epilogue: +bias, relu, bf16; permuted cols -> contiguous-d stores */
#pragma unroll
  for (int j = 0; j < 4; ++j) {
    const int cblk = wn * 64 + j * 16;
    const int o = rowB0 + (cblk & ~31) + 2 * lr + ((cblk >> 4) & 1);
    const float bv = bff[o];
    const int label = o >> 9, d = (o >> 1) & 255, se = o & 1;
    u16* dst = se ? ef : sf;
#pragma unroll
    for (int i = 0; i < 8; ++i) {
#pragma unroll
      for (int r = 0; r < 4; ++r) {
        const int m = rowA0 + wm * 128 + i * 16 + hi * 4 + r;
        const int b = m >> 9, ll = m & 511;
        float v = acc[i][j][r] + bv;
        v = v > 0.f ? v : 0.f;
        dst[((long)(b * NLAB + label) * LSEQ + ll) * LDIM + d] = f2bf(v);
      }
    }
  }
}

/* === Biaffine: 256^2 tile, e-split 2-pass (256x128 acc), 2 blocks/CU ======== */
/* granule swizzle (r4-verified): granule g holds global (row g>>2,
   col-granule (g&3)^((g>>3)&3)); LDS dest linear g*16B; read of frag
   (row r, k-granule hi) at granule 4r + (hi^((r>>1)&3)) -> 2-way max. */
#define RD_OFF(r, hi) ((4 * (r) + ((hi) ^ (((r) >> 1) & 3))) * 8)

__global__ __launch_bounds__(512, 4)
void biaffine256s(const u16* __restrict__ sf, const u16* __restrict__ ef,
                  const float* __restrict__ bias, const int* __restrict__ mask,
                  float* __restrict__ out) {
  /* per buf: A region [0, 8192) u16 (256x32), B region [8192, 12288) (128x32) */
  __shared__ __align__(16) u16 lds[2][12288];     /* 48 KiB */
  const int tid = threadIdx.x, lane = tid & 63, wv = tid >> 6;
  const int wm = wv >> 2, wn = wv & 3;            /* 2 x 4 waves; wave = 128s x 32e */
  const int lr = lane & 15, hi = lane >> 4;

  const int bid = blockIdx.x;
  const int wg  = (bid & 7) * 96 + (bid >> 3);    /* 4 tiles of a bl share an XCD */
  const int bl  = wg >> 2, tile = wg & 3;
  const int tm  = tile >> 1, tn = tile & 1;
  const int b = bl / NLAB, label = bl - b * NLAB;
  const u16* Ab = sf + (long)bl * LSEQ * LDIM;
  const u16* Bb = ef + (long)bl * LSEQ * LDIM;
  const int rowA0 = tm * 256, rowB0 = tn * 256;

  /* A staging: 2 loads/thread (1024 granules); B-half: 1 load (512 granules) */
  const u16* gAa[2]; int dstA[2];
#pragma unroll
  for (int L = 0; L < 2; ++L) {
    const int g = L * 512 + tid;
    const int r = g >> 2;
    const int c = (g & 3) ^ ((g >> 3) & 3);
    gAa[L] = Ab + (long)(rowA0 + r) * LDIM + c * 8;
    dstA[L] = g * 8;
  }
  const int rb = tid >> 2;
  const int cb = (tid & 3) ^ ((tid >> 3) & 3);
  const u16* gB0 = Bb + (long)(rowB0 + rb) * LDIM + cb * 8;
  const int dstB = 8192 + tid * 8;

  int offA[8], offB[2];
#pragma unroll
  for (int i = 0; i < 8; ++i) offA[i] = RD_OFF(wm * 128 + i * 16 + lr, hi);
#pragma unroll
  for (int j = 0; j < 2; ++j) offB[j] = 8192 + RD_OFF(wn * 32 + j * 16 + lr, hi);

  const float bv = bias[label];
  const long obase = (long)bl * LSEQ * LSEQ;

#pragma unroll 1
  for (int ph = 0; ph < 2; ++ph) {
    const u16* gBp = gB0 + (long)ph * 128 * LDIM;
    const int ebase = rowB0 + ph * 128;

    f32x4 acc[8][2] = {};

    /* prologue: stage K-tile 0 into buf 0 */
#pragma unroll
    for (int L = 0; L < 2; ++L) g2l16(gAa[L], &lds[0][dstA[L]]);
    g2l16(gBp, &lds[0][dstB]);
    __syncthreads();

#pragma unroll 1
    for (int t = 0; t < 8; ++t) {
      if (t < 7) {
        const int ko = (t + 1) * 32, nb = (t + 1) & 1;
#pragma unroll
        for (int L = 0; L < 2; ++L) g2l16(gAa[L] + ko, &lds[nb][dstA[L]]);
        g2l16(gBp + ko, &lds[nb][dstB]);
      }
      const u16* Lc = lds[t & 1];
      short8 bfr[2];
#pragma unroll
      for (int j = 0; j < 2; ++j) bfr[j] = *reinterpret_cast<const short8*>(Lc + offB[j]);
      __builtin_amdgcn_s_setprio(1);
#pragma unroll
      for (int ihalf = 0; ihalf < 2; ++ihalf) {
        short8 a4[4];
#pragma unroll
        for (int i = 0; i < 4; ++i) a4[i] = *reinterpret_cast<const short8*>(Lc + offA[ihalf * 4 + i]);
#pragma unroll
        for (int i = 0; i < 4; ++i)
#pragma unroll
          for (int j = 0; j < 2; ++j)
            acc[ihalf * 4 + i][j] = __builtin_amdgcn_mfma_f32_16x16x32_bf16(a4[i], bfr[j], acc[ihalf * 4 + i][j], 0, 0, 0);
      }
      __builtin_amdgcn_s_setprio(0);
      __syncthreads();
    }

    /* store this e-half; stores drain under the other block / next phase */
    bool me[2];
#pragma unroll
    for (int j = 0; j < 2; ++j) me[j] = (mask[b * LSEQ + ebase + wn * 32 + j * 16 + lr] != 0);
#pragma unroll
    for (int i = 0; i < 8; ++i) {
#pragma unroll
      for (int r = 0; r < 4; ++r) {
        const int s = rowA0 + wm * 128 + i * 16 + hi * 4 + r;
        const bool ms = (mask[b * LSEQ + s] != 0);
        const long rbase = obase + (long)s * LSEQ;
#pragma unroll
        for (int j = 0; j < 2; ++j) {
          const int e = ebase + wn * 32 + j * 16 + lr;
          float v = acc[i][j][r] + bv;
          u32 bits = __builtin_bit_cast(u32, v);
          if ((bits & 0x7F800000u) == 0x7F800000u) v = NEGV;  /* inf or nan */
          out[rbase + e] = v;
          const bool keep = (s <= e) && ms && me[j];
          out[MOFF + rbase + e] = keep ? v : NEGV;
        }
      }
    }
  }
}

extern "C" void kernel_launch(void* const* d_in, const int* in_sizes, int n_in,
                              void* d_out, int out_size, void* d_ws, size_t ws_size,
                              hipStream_t stream) {
  const float* feat = (const float*)d_in[0];
  const int*   mask = (const int*)d_in[1];
  const float* wff  = (const float*)d_in[2];
  const float* bff  = (const float*)d_in[3];
  const float* bias = (const float*)d_in[4];
  float* out = (float*)d_out;

  u16* fA = (u16*)d_ws;                 /*  4,194,304 elems =  8 MiB  */
  u16* fB = fA + 4194304L;              /* 12,582,912 elems = 24 MiB  */
  u16* sf = fB + 12582912L;             /* 25,165,824 elems = 48 MiB  */
  u16* ef = sf + 25165824L;             /* 25,165,824 elems = 48 MiB  */

  cvt_bf16_kernel<<<2048, 256, 0, stream>>>(feat, wff, fA, fB);
  ff_gemm256<<<768, 512, 0, stream>>>(fA, fB, bff, sf, ef);
  biaffine256s<<<768, 512, 0, stream>>>(sf, ef, bias, mask, out);
}

// Round 8
// 258.672 us; speedup vs baseline: 1.4691x; 1.4691x over previous
//
#include <hip/hip_runtime.h>
#include <hip/hip_bf16.h>

#define NLAB  24
#define LDIM  256
#define LSEQ  512
#define DDIM  1024
#define NOUT  12288            /* NLAB*LDIM*2 */
#define NEGV  (-10000.0f)
#define MOFF  50331648L        /* 192*512*512 */

typedef __attribute__((ext_vector_type(8))) short short8;
typedef __attribute__((ext_vector_type(4))) float f32x4;
typedef unsigned short u16;
typedef unsigned int   u32;

typedef const __attribute__((address_space(1))) void gvoid_t;
typedef __attribute__((address_space(3))) void lvoid_t;

__device__ __forceinline__ u16 f2bf(float f) {
  u32 u = __builtin_bit_cast(u32, f);
  u32 r = u + 0x7FFFu + ((u >> 16) & 1u);
  return (u16)(r >> 16);
}

__device__ __forceinline__ void g2l16(const u16* g, u16* l) {
  __builtin_amdgcn_global_load_lds((gvoid_t*)g, (lvoid_t*)l, 16, 0, 0);
}

/* ---------------- fp32 -> bf16 conversion of features and w_ff ------------- */
__global__ void cvt_bf16_kernel(const float* __restrict__ feat,
                                const float* __restrict__ wff,
                                u16* __restrict__ fA, u16* __restrict__ fB) {
  const long NA = 4194304L;      /* 4096*1024 */
  const long NB = 12582912L;     /* 12288*1024 */
  const long NQ = (NA + NB) / 4;
  long stride = (long)gridDim.x * blockDim.x;
  for (long i = (long)blockIdx.x * blockDim.x + threadIdx.x; i < NQ; i += stride) {
    long e = i * 4;
    const float* s; u16* d;
    if (e < NA) { s = feat + e;        d = fA + e; }
    else        { s = wff + (e - NA);  d = fB + (e - NA); }
    float4 v = *reinterpret_cast<const float4*>(s);
    ushort4 o;
    o.x = f2bf(v.x); o.y = f2bf(v.y); o.z = f2bf(v.z); o.w = f2bf(v.w);
    *reinterpret_cast<ushort4*>(d) = o;
  }
}

/* ---- r2-verbatim FF GEMM: 256^2 tile, BK=64, 2-phase, 128KB LDS ----------- */
template<int LDK, bool PERM>
__device__ __forceinline__ void stage_tile(const u16* __restrict__ gbase, int row0,
                                           int k0, u16* lbuf, int t) {
#pragma unroll
  for (int l = 0; l < 4; ++l) {
    const int rt = l * 64 + (t >> 3);
    const int ce = ((t & 7) ^ (rt & 7)) << 3;
    int gr = rt;
    if (PERM) gr = (rt & ~31) | ((rt & 15) << 1) | ((rt >> 4) & 1);
    g2l16(gbase + (long)(row0 + gr) * LDK + k0 + ce, lbuf + (l * 512 + t) * 8);
  }
}

#define FRAG_OFF(r, ks, hi) (((r) * 64 + (ks) * 32 + (hi) * 8) ^ (((r) & 7) << 3))

__global__ __launch_bounds__(512, 2)
void ff_gemm256(const u16* __restrict__ A, const u16* __restrict__ B,
                const float* __restrict__ bff,
                u16* __restrict__ sf, u16* __restrict__ ef) {
  __shared__ __align__(16) u16 lds[2][2][16384];    /* 128 KiB */
  const int tid = threadIdx.x, lane = tid & 63, wv = tid >> 6;
  const int wm = wv >> 2, wn = wv & 3;
  const int lr = lane & 15, hi = lane >> 4;

  const int bid = blockIdx.x;
  const int wg  = (bid & 7) * 96 + (bid >> 3);      /* XCD-chunked, bijective */
  const int tm  = wg & 15, tn = wg >> 4;            /* 16 x 48 tiles */
  const int rowA0 = tm * 256, rowB0 = tn * 256;

  f32x4 acc[8][4] = {};

  stage_tile<DDIM, false>(A, rowA0, 0, lds[0][0], tid);
  stage_tile<DDIM, true >(B, rowB0, 0, lds[0][1], tid);
  __syncthreads();

  int buf = 0;
  for (int t = 0; t < 16; ++t) {
    if (t < 15) {
      stage_tile<DDIM, false>(A, rowA0, (t + 1) * 64, lds[buf ^ 1][0], tid);
      stage_tile<DDIM, true >(B, rowB0, (t + 1) * 64, lds[buf ^ 1][1], tid);
    }
    const u16* La = lds[buf][0];
    const u16* Lb = lds[buf][1];
#pragma unroll
    for (int ks = 0; ks < 2; ++ks) {
      short8 af[8], bfr[4];
#pragma unroll
      for (int i = 0; i < 8; ++i) {
        const int r = wm * 128 + i * 16 + lr;
        af[i] = *reinterpret_cast<const short8*>(La + FRAG_OFF(r, ks, hi));
      }
#pragma unroll
      for (int j = 0; j < 4; ++j) {
        const int r = wn * 64 + j * 16 + lr;
        bfr[j] = *reinterpret_cast<const short8*>(Lb + FRAG_OFF(r, ks, hi));
      }
      __builtin_amdgcn_s_setprio(1);
#pragma unroll
      for (int i = 0; i < 8; ++i)
#pragma unroll
        for (int j = 0; j < 4; ++j)
          acc[i][j] = __builtin_amdgcn_mfma_f32_16x16x32_bf16(af[i], bfr[j], acc[i][j], 0, 0, 0);
      __builtin_amdgcn_s_setprio(0);
    }
    __syncthreads();
    buf ^= 1;
  }

  /* epilogue: +bias, relu, bf16; permuted cols -> contiguous-d stores */
#pragma unroll
  for (int j = 0; j < 4; ++j) {
    const int cblk = wn * 64 + j * 16;
    const int o = rowB0 + (cblk & ~31) + 2 * lr + ((cblk >> 4) & 1);
    const float bv = bff[o];
    const int label = o >> 9, d = (o >> 1) & 255, se = o & 1;
    u16* dst = se ? ef : sf;
#pragma unroll
    for (int i = 0; i < 8; ++i) {
#pragma unroll
      for (int r = 0; r < 4; ++r) {
        const int m = rowA0 + wm * 128 + i * 16 + hi * 4 + r;
        const int b = m >> 9, ll = m & 511;
        float v = acc[i][j][r] + bv;
        v = v > 0.f ? v : 0.f;
        dst[((long)(b * NLAB + label) * LSEQ + ll) * LDIM + d] = f2bf(v);
      }
    }
  }
}

/* ==== Biaffine: 128^2 tile, FULL-K (256) single-stage, 128KB LDS, 1 sync ==== */
/* LDS layout per matrix: 128 rows x 32 granules(16B); granule (row,c) holds
   global k-granule c ^ (row&31). Read frag (row r, ks, hi) at granule
   (ks*4+hi) ^ (r&31): 16 lanes -> 16 distinct c, 2-way bank max.          */
__global__ __launch_bounds__(256)
void biaffine128f(const u16* __restrict__ sf, const u16* __restrict__ ef,
                  const float* __restrict__ bias, const int* __restrict__ mask,
                  float* __restrict__ out) {
  __shared__ __align__(16) u16 lds[65536];        /* A: [0,32768), B: [32768,65536) */
  const int tid = threadIdx.x, lane = tid & 63, wv = tid >> 6;
  const int wm = wv >> 1, wn = wv & 1;
  const int lr = lane & 15, hi = lane >> 4;

  const int bid = blockIdx.x;
  const int wg  = (bid & 7) * 384 + (bid >> 3);   /* 3072 = 8*384; 24 bl per XCD */
  const int bl  = wg >> 4, tile = wg & 15;
  const int tm  = tile >> 2, tn = tile & 3;
  const int b = bl / NLAB, label = bl - b * NLAB;
  const u16* Ab = sf + ((long)bl * LSEQ + tm * 128) * LDIM;
  const u16* Bb = ef + ((long)bl * LSEQ + tn * 128) * LDIM;

  /* stage full 128x256 A and B panels: 16 loads/thread each, one barrier */
  {
    const int r0 = tid >> 5, c0 = tid & 31;
#pragma unroll
    for (int L = 0; L < 16; ++L) {
      const int row = r0 + 8 * L;
      const int cg  = c0 ^ (row & 31);
      const long go = (long)row * LDIM + cg * 8;
      const int  dd = (row * 32 + c0) * 8;
      g2l16(Ab + go, &lds[dd]);
      g2l16(Bb + go, &lds[32768 + dd]);
    }
  }
  __syncthreads();

  /* frag base offsets (u16 idx): row*256; per-ks granule XOR applied inline */
  int rA[4], rB[4];
#pragma unroll
  for (int i = 0; i < 4; ++i) rA[i] = wm * 64 + i * 16 + lr;
#pragma unroll
  for (int j = 0; j < 4; ++j) rB[j] = wn * 64 + j * 16 + lr;

  f32x4 acc[4][4] = {};
#pragma unroll
  for (int ks = 0; ks < 8; ++ks) {
    short8 af[4], bfr[4];
#pragma unroll
    for (int i = 0; i < 4; ++i) {
      const int off = rA[i] * 256 + (((ks * 4 + hi) ^ (rA[i] & 31)) << 3);
      af[i] = *reinterpret_cast<const short8*>(&lds[off]);
    }
#pragma unroll
    for (int j = 0; j < 4; ++j) {
      const int off = rB[j] * 256 + (((ks * 4 + hi) ^ (rB[j] & 31)) << 3);
      bfr[j] = *reinterpret_cast<const short8*>(&lds[32768 + off]);
    }
    __builtin_amdgcn_s_setprio(1);
#pragma unroll
    for (int i = 0; i < 4; ++i)
#pragma unroll
      for (int j = 0; j < 4; ++j)
        acc[i][j] = __builtin_amdgcn_mfma_f32_16x16x32_bf16(af[i], bfr[j], acc[i][j], 0, 0, 0);
    __builtin_amdgcn_s_setprio(0);
  }

  /* store phase: fire-and-forget; drains under later blocks' stage/compute */
  const float bv = bias[label];
  const long obase = (long)bl * LSEQ * LSEQ;
  const int rowA0 = tm * 128, rowB0 = tn * 128;
  bool me[4];
#pragma unroll
  for (int j = 0; j < 4; ++j) me[j] = (mask[b * LSEQ + rowB0 + wn * 64 + j * 16 + lr] != 0);
#pragma unroll
  for (int i = 0; i < 4; ++i) {
#pragma unroll
    for (int r = 0; r < 4; ++r) {
      const int s = rowA0 + wm * 64 + i * 16 + hi * 4 + r;
      const bool ms = (mask[b * LSEQ + s] != 0);
      const long rbase = obase + (long)s * LSEQ;
#pragma unroll
      for (int j = 0; j < 4; ++j) {
        const int e = rowB0 + wn * 64 + j * 16 + lr;
        float v = acc[i][j][r] + bv;
        u32 bits = __builtin_bit_cast(u32, v);
        if ((bits & 0x7F800000u) == 0x7F800000u) v = NEGV;  /* inf or nan */
        out[rbase + e] = v;
        const bool keep = (s <= e) && ms && me[j];
        out[MOFF + rbase + e] = keep ? v : NEGV;
      }
    }
  }
}

extern "C" void kernel_launch(void* const* d_in, const int* in_sizes, int n_in,
                              void* d_out, int out_size, void* d_ws, size_t ws_size,
                              hipStream_t stream) {
  const float* feat = (const float*)d_in[0];
  const int*   mask = (const int*)d_in[1];
  const float* wff  = (const float*)d_in[2];
  const float* bff  = (const float*)d_in[3];
  const float* bias = (const float*)d_in[4];
  float* out = (float*)d_out;

  u16* fA = (u16*)d_ws;                 /*  4,194,304 elems =  8 MiB  */
  u16* fB = fA + 4194304L;              /* 12,582,912 elems = 24 MiB  */
  u16* sf = fB + 12582912L;             /* 25,165,824 elems = 48 MiB  */
  u16* ef = sf + 25165824L;             /* 25,165,824 elems = 48 MiB  */

  cvt_bf16_kernel<<<2048, 256, 0, stream>>>(feat, wff, fA, fB);
  ff_gemm256<<<768, 512, 0, stream>>>(fA, fB, bff, sf, ef);
  biaffine128f<<<3072, 256, 0, stream>>>(sf, ef, bias, mask, out);
}